// Round 2
// baseline (256.939 us; speedup 1.0000x reference)
//
#include <hip/hip_runtime.h>

// FlyHash-style sparse projection + per-row top-k threshold.
//
// Round 2: x must BIT-MATCH the reference. Ref computes f32 einsum with
// fold-left ascending-k accumulation (np serial / BLAS sgemm); products are
// exact (W in {0,1}) and zeros are exact identities, so ref x = serial f32
// sum of the <=6 selected inputs in ASCENDING INDEX ORDER. Round 1 used an
// exact double sum (correctly-rounded f32) -> 1-2 ULP off ref -> rank-32
// boundary flip (absmax 4.9 = a boundary element's value). Fix: serial f32
// adds, ascending, pads (=0.0f) last. Threshold = exact 32nd-largest bit
// pattern of OUR x == ref's thresh on identical x -> identical mask.

constexpr int IN_F   = 512;
constexpr int OUT_F  = 10240;
constexpr int TPB    = 512;
constexpr int VPT    = OUT_F / TPB;   // 20 values per thread
constexpr int NBINS  = 2048;          // value-histogram bins over [0, 8)
constexpr int NCHUNK = NBINS / 4;     // 512 chunk sums, one per thread
constexpr int NWAVES = TPB / 64;      // 8

static_assert(NCHUNK == TPB, "chunk scan assumes one chunk per thread");

// ---------------------------------------------------------------------------
// Kernel 1: extract sparse indices from dense W. One wave per W row.
// Emits indices in ASCENDING order (ctz scan, low chunk first) — required
// for bit-exact fold-left accumulation downstream.
// ---------------------------------------------------------------------------
__global__ __launch_bounds__(256) void extract_idx(const float* __restrict__ W,
                                                   uint4* __restrict__ packed,
                                                   int out_f) {
  int row  = blockIdx.x * 4 + (threadIdx.x >> 6);
  int lane = threadIdx.x & 63;
  if (row >= out_f) return;

  const float* wr = W + (size_t)row * IN_F;
  unsigned long long masks[8];
#pragma unroll
  for (int c = 0; c < 8; ++c) {
    float v = wr[c * 64 + lane];
    masks[c] = __ballot(v != 0.0f);   // entries are exactly 0.0 or 1.0
  }
  if (lane == 0) {
    unsigned idx[6] = {IN_F, IN_F, IN_F, IN_F, IN_F, IN_F};  // pad -> zero slot
    int n = 0;
#pragma unroll
    for (int c = 0; c < 8; ++c) {
      unsigned long long m = masks[c];
      while (m && n < 6) {
        int b = __builtin_ctzll(m);
        idx[n++] = (unsigned)(c * 64 + b);
        m &= m - 1;
      }
    }
    uint4 r;
    r.x = idx[0] | (idx[1] << 16);
    r.y = idx[2] | (idx[3] << 16);
    r.z = idx[4] | (idx[5] << 16);
    r.w = (unsigned)n;
    packed[row] = r;
  }
}

// ---------------------------------------------------------------------------
// Kernel 2: per batch row: compute x, exact top-k threshold, thresholded write
// ---------------------------------------------------------------------------
__global__ __launch_bounds__(TPB) void fly_hash(const float* __restrict__ inp,
                                                const uint4* __restrict__ packed,
                                                const int* __restrict__ kptr,
                                                float* __restrict__ out) {
  __shared__ float inRow[IN_F + 1];   // [IN_F] = 0.0f zero slot for pad indices
  __shared__ int   hist[NBINS];
  __shared__ int   csum[NCHUNK];
  __shared__ int   wsum[NWAVES];
  __shared__ unsigned sh_bstar;

  const int tid = threadIdx.x;
  const int row = blockIdx.x;
  const int k   = *kptr;              // hash_length (32)

  // --- stage input row + zero histogram --------------------------------
  if (tid < IN_F) inRow[tid] = inp[(size_t)row * IN_F + tid];
  if (tid == 0)   inRow[IN_F] = 0.0f;
  for (int i = tid; i < NBINS; i += TPB) hist[i] = 0;
  __syncthreads();

  // --- compute x (registers) + value histogram -------------------------
  // BIT-EXACT vs ref: serial f32 fold-left in ascending index order.
  // Pads point at inRow[IN_F]=0.0f; x>=0 so +0.0f is an exact identity.
  // x in [0,6) -> histogram key floor(x*256) (exact: *256 is a pow2 scale).
  float x[VPT];
#pragma unroll
  for (int i = 0; i < VPT; ++i) {
    uint4 r = packed[tid + i * TPB];
    float s = inRow[r.x & 0xFFFFu];
    s += inRow[r.x >> 16];
    s += inRow[r.y & 0xFFFFu];
    s += inRow[r.y >> 16];
    s += inRow[r.z & 0xFFFFu];
    s += inRow[r.z >> 16];
    x[i] = s;
    int bin = (int)(s * 256.0f);
    bin = bin < 0 ? 0 : (bin > NBINS - 1 ? NBINS - 1 : bin);
    atomicAdd(&hist[bin], 1);
  }
  __syncthreads();

  // --- find bracket bin: max b with suffix-count(b) >= k ----------------
  {
    int b0 = tid * 4;
    csum[tid] = hist[b0] + hist[b0 + 1] + hist[b0 + 2] + hist[b0 + 3];
  }
  __syncthreads();
  // in-place Hillis-Steele suffix scan over 512 chunk sums
  for (int s = 1; s < NCHUNK; s <<= 1) {
    int v = csum[tid] + ((tid + s < NCHUNK) ? csum[tid + s] : 0);
    __syncthreads();
    csum[tid] = v;
    __syncthreads();
  }
  {
    int above = (tid + 1 < NCHUNK) ? csum[tid + 1] : 0;
    if (csum[tid] >= k && above < k) {      // unique crossing chunk
      int acc = above;
      unsigned bsel = (unsigned)(tid * 4);
      for (int b = tid * 4 + 3; b >= tid * 4; --b) {
        acc += hist[b];
        if (acc >= k) { bsel = (unsigned)b; break; }
      }
      sh_bstar = bsel;
    }
  }
  __syncthreads();

  // --- exact threshold: bit-level binary search inside the bracket ------
  // Non-negative f32: uint bit order == value order. Find max u with
  // count(x >= u) >= k  ->  u is exactly the k-th largest value's bits.
  const unsigned bstar = sh_bstar;
  unsigned lo = __float_as_uint((float)bstar * (1.0f / 256.0f));
  lo = (lo >= 8u) ? lo - 8u : 0u;                                   // slop
  unsigned hi = __float_as_uint((float)(bstar + 1) * (1.0f / 256.0f)) + 8u;

  const int lane = tid & 63;
  const int wid  = tid >> 6;
  while (lo < hi) {
    unsigned mid = lo + ((hi - lo + 1u) >> 1);
    float fm = __uint_as_float(mid);
    int c = 0;
#pragma unroll
    for (int i = 0; i < VPT; ++i)
      c += (int)__popcll(__ballot(x[i] >= fm));   // wave-total, no LDS
    if (lane == 0) wsum[wid] = c;
    __syncthreads();
    int total = 0;
#pragma unroll
    for (int w = 0; w < NWAVES; ++w) total += wsum[w];
    if (total >= k) lo = mid; else hi = mid - 1;  // uniform across block
    __syncthreads();
  }
  const float t = __uint_as_float(lo);

  // --- thresholded write, coalesced from registers ----------------------
  float* orow = out + (size_t)row * OUT_F;
#pragma unroll
  for (int i = 0; i < VPT; ++i) {
    float v = x[i];
    orow[tid + i * TPB] = (v >= t) ? v : 0.0f;
  }
}

// ---------------------------------------------------------------------------
extern "C" void kernel_launch(void* const* d_in, const int* in_sizes, int n_in,
                              void* d_out, int out_size, void* d_ws, size_t ws_size,
                              hipStream_t stream) {
  const float* inp = (const float*)d_in[0];
  const float* W   = (const float*)d_in[1];
  const int* kptr  = (const int*)d_in[2];
  float* out       = (float*)d_out;

  const int batch = in_sizes[0] / IN_F;   // 4096
  const int out_f = in_sizes[1] / IN_F;   // 10240

  uint4* packed = (uint4*)d_ws;           // 10240 * 16 B = 160 KB scratch

  hipLaunchKernelGGL(extract_idx, dim3((out_f + 3) / 4), dim3(256), 0, stream,
                     W, packed, out_f);
  hipLaunchKernelGGL(fly_hash, dim3(batch), dim3(TPB), 0, stream,
                     inp, packed, kptr, out);
}